// Round 1
// baseline (114.162 us; speedup 1.0000x reference)
//
#include <hip/hip_runtime.h>
#include <hip/hip_bf16.h>
#include <cstddef>

// ---------------------------------------------------------------------------
// HardActor: fused regime-routed MLP
//   h     = relu(x @ W1 + b1)            [B,256]
//   feats = relu(h @ W2 + b2)            [B,256]
//   raw   = feats @ Wh[regime] + bh[regime]   (regime = (int)x[:,255])
//   mean  = 0.1 * raw                    [B,128]
//   std   = clip(exp(log_std), 1e-3, 1)  broadcast [B,128]
//
// Strategy: bf16 MFMA (16x16x32) end-to-end, weights pre-transposed+converted
// to bf16 in d_ws (prep kernel). Main kernel: 64 rows/block, 4 waves; waves
// partition N. Head is computed densely as [256 x 512] (4 heads concat along
// N) => wave w owns head w; epilogue writes only rows with regime == w.
// ---------------------------------------------------------------------------

typedef unsigned short u16;
typedef unsigned int   u32;

using bf16x8 = __attribute__((ext_vector_type(8))) __bf16;
using f32x4  = __attribute__((ext_vector_type(4))) float;

#define BM    64
#define LDSW  264   // 256 + 8 bf16 pad: keeps 16B row alignment, breaks bank aliasing

__device__ __forceinline__ u16 f2bf(float f) {
  union { float f; u32 u; } v; v.f = f;
  u32 u = v.u;
  return (u16)((u + 0x7FFFu + ((u >> 16) & 1u)) >> 16);
}

// ws layout (u16 elements): [0)      W1t[n][k]   256x256
//                           [65536)  W2t[n][k]   256x256
//                           [131072) Wht[c][k]   512x256, c = r*128 + a
__global__ void prep_weights(const float* __restrict__ W1,
                             const float* __restrict__ W2,
                             const float* __restrict__ Wh,
                             u16* __restrict__ ws) {
  int i = blockIdx.x * 256 + threadIdx.x;          // 65536 threads
  int n = i >> 8, k = i & 255;
  ws[i]         = f2bf(W1[k * 256 + n]);           // W1t[n][k] = W1[k][n]
  ws[65536 + i] = f2bf(W2[k * 256 + n]);
#pragma unroll
  for (int t = 0; t < 2; ++t) {
    int idx = i + t * 65536;                        // 131072 elems
    int c = idx >> 8, h = idx & 255;
    int r = c >> 7, a = c & 127;
    ws[131072 + idx] = f2bf(Wh[(r * 256 + h) * 128 + a]);  // Wht[c][h]
  }
}

// One 64x256x(K=256) GEMM: O = relu(A @ Wt^T + bias), A/O bf16 in LDS.
// Wave `wave` computes cols [wave*64, wave*64+64).
__device__ __forceinline__ void gemm_256(const u16* A, const u16* __restrict__ Wt,
                                         const float* __restrict__ bias, u16* O,
                                         int wave, int ar, int kg, int orow) {
  f32x4 acc[4][4] = {};
  const int n0 = wave * 64;
#pragma unroll
  for (int kk = 0; kk < 8; ++kk) {
    const int k = kk * 32 + kg;
    bf16x8 a[4], b[4];
#pragma unroll
    for (int m = 0; m < 4; ++m)
      a[m] = *(const bf16x8*)&A[(m * 16 + ar) * LDSW + k];
#pragma unroll
    for (int n = 0; n < 4; ++n)
      b[n] = *(const bf16x8*)&Wt[(n0 + n * 16 + ar) * 256 + k];
#pragma unroll
    for (int m = 0; m < 4; ++m)
#pragma unroll
      for (int n = 0; n < 4; ++n)
        acc[m][n] = __builtin_amdgcn_mfma_f32_16x16x32_bf16(a[m], b[n], acc[m][n], 0, 0, 0);
  }
#pragma unroll
  for (int n = 0; n < 4; ++n) {
    const int col = n0 + n * 16 + ar;
    const float bv = bias[col];
#pragma unroll
    for (int m = 0; m < 4; ++m) {
#pragma unroll
      for (int j = 0; j < 4; ++j) {
        float v = acc[m][n][j] + bv;
        v = v > 0.f ? v : 0.f;
        O[(m * 16 + orow + j) * LDSW + col] = f2bf(v);
      }
    }
  }
}

__global__ __launch_bounds__(256, 2) void actor_main(
    const float* __restrict__ x,
    const float* __restrict__ b1, const float* __restrict__ b2,
    const float* __restrict__ bh, const float* __restrict__ log_std,
    const u16* __restrict__ wbf,
    float* __restrict__ out_mean, float* __restrict__ out_std) {
  __shared__ u16 bufA[BM * LDSW];   // x, later feats
  __shared__ u16 bufB[BM * LDSW];   // h
  __shared__ int s_regime[BM];

  const int tid  = threadIdx.x;
  const int lane = tid & 63;
  const int wave = tid >> 6;
  const int row0 = blockIdx.x * BM;
  const int ar   = lane & 15;          // row/col within 16-frag
  const int kg   = (lane >> 4) * 8;    // k sub-offset within 32-chunk
  const int orow = (lane >> 4) * 4;    // C/D row group

  // ---- phase 0: stage x -> bf16 LDS; capture regime from col 255 ----
  {
    const float4* xg = (const float4*)(x + (size_t)row0 * 256);
    for (int i = tid; i < BM * 64; i += 256) {
      float4 v = xg[i];
      int row = i >> 6, c4 = (i & 63) << 2;
      ushort4 b;
      b.x = f2bf(v.x); b.y = f2bf(v.y); b.z = f2bf(v.z); b.w = f2bf(v.w);
      *(ushort4*)&bufA[row * LDSW + c4] = b;
      if (c4 == 252) s_regime[row] = (int)v.w;
    }
  }
  __syncthreads();

  // ---- GEMM1: x @ W1 -> h (bufB) ----
  gemm_256(bufA, wbf, b1, bufB, wave, ar, kg, orow);
  __syncthreads();

  // ---- GEMM2: h @ W2 -> feats (bufA) ----
  gemm_256(bufB, wbf + 65536, b2, bufA, wave, ar, kg, orow);
  __syncthreads();

  // ---- GEMM3: feats @ Wht (N=512: 4 heads concat); wave w owns head w ----
  {
    const u16* Wht = wbf + 131072;
    f32x4 acc[4][8] = {};
    const int n0 = wave * 128;
#pragma unroll
    for (int kk = 0; kk < 8; ++kk) {
      const int k = kk * 32 + kg;
      bf16x8 a[4];
#pragma unroll
      for (int m = 0; m < 4; ++m)
        a[m] = *(const bf16x8*)&bufA[(m * 16 + ar) * LDSW + k];
#pragma unroll
      for (int n = 0; n < 8; ++n) {
        bf16x8 b = *(const bf16x8*)&Wht[(n0 + n * 16 + ar) * 256 + k];
#pragma unroll
        for (int m = 0; m < 4; ++m)
          acc[m][n] = __builtin_amdgcn_mfma_f32_16x16x32_bf16(a[m], b, acc[m][n], 0, 0, 0);
      }
    }
    // epilogue: this wave's cols all belong to head `wave`
    const int rblk = wave;
#pragma unroll
    for (int n = 0; n < 8; ++n) {
      const int acol = n * 16 + ar;               // 0..127 within head
      const float bhv = bh[rblk * 128 + acol];
#pragma unroll
      for (int m = 0; m < 4; ++m) {
#pragma unroll
        for (int j = 0; j < 4; ++j) {
          const int row = m * 16 + orow + j;
          if (s_regime[row] == rblk)
            out_mean[(size_t)(row0 + row) * 128 + acol] = 0.1f * (acc[m][n][j] + bhv);
        }
      }
    }
  }

  // ---- std: same 128-vector for every row ----
  for (int i = tid; i < BM * 32; i += 256) {
    int row = i >> 5, c4 = (i & 31) << 2;
    float4 s;
    s.x = fminf(fmaxf(expf(log_std[c4 + 0]), 1e-3f), 1.0f);
    s.y = fminf(fmaxf(expf(log_std[c4 + 1]), 1e-3f), 1.0f);
    s.z = fminf(fmaxf(expf(log_std[c4 + 2]), 1e-3f), 1.0f);
    s.w = fminf(fmaxf(expf(log_std[c4 + 3]), 1e-3f), 1.0f);
    *(float4*)&out_std[(size_t)(row0 + row) * 128 + c4] = s;
  }
}

extern "C" void kernel_launch(void* const* d_in, const int* in_sizes, int n_in,
                              void* d_out, int out_size, void* d_ws, size_t ws_size,
                              hipStream_t stream) {
  const float* x  = (const float*)d_in[0];
  const float* W1 = (const float*)d_in[1];
  const float* b1 = (const float*)d_in[2];
  const float* W2 = (const float*)d_in[3];
  const float* b2 = (const float*)d_in[4];
  const float* Wh = (const float*)d_in[5];
  const float* bh = (const float*)d_in[6];
  const float* ls = (const float*)d_in[7];

  const int B = in_sizes[0] / 256;          // 65536
  float* out_mean = (float*)d_out;
  float* out_std  = out_mean + (size_t)B * 128;
  u16* wbf = (u16*)d_ws;                    // needs 512 KiB

  hipLaunchKernelGGL(prep_weights, dim3(256), dim3(256), 0, stream, W1, W2, Wh, wbf);
  hipLaunchKernelGGL(actor_main, dim3(B / BM), dim3(256), 0, stream,
                     x, b1, b2, bh, ls, wbf, out_mean, out_std);
}

// Round 2
// 107.155 us; speedup vs baseline: 1.0654x; 1.0654x over previous
//
#include <hip/hip_runtime.h>
#include <hip/hip_bf16.h>
#include <cstddef>

// ---------------------------------------------------------------------------
// HardActor: fused regime-routed MLP (bf16 MFMA end-to-end)
//   h     = relu(x @ W1 + b1)            [B,256]
//   feats = relu(h @ W2 + b2)            [B,256]
//   raw   = feats @ Wh[regime] + bh[regime]   (regime = (int)x[:,255])
//   mean  = 0.1 * raw                    [B,128]
//   std   = clip(exp(log_std), 1e-3, 1)  broadcast [B,128]
//
// R2: 512 threads (8 waves) per block sharing the same 68 KB LDS footprint
// as R1's 256 -> occupancy cap 25%->50% (2 blocks/CU x 8 waves). Waves split
// N 8-ways in GEMM1/2 (32 cols) and GEMM3 (64 cols; wave w owns head w>>1).
// std-write moved before the first barrier to overlap staging latency.
// ---------------------------------------------------------------------------

typedef unsigned short u16;
typedef unsigned int   u32;

using bf16x8 = __attribute__((ext_vector_type(8))) __bf16;
using f32x4  = __attribute__((ext_vector_type(4))) float;

#define BM      64
#define LDSW    264   // 256 + 8 bf16 pad: 16B row alignment, breaks bank aliasing
#define THREADS 512

__device__ __forceinline__ u16 f2bf(float f) {
  union { float f; u32 u; } v; v.f = f;
  u32 u = v.u;
  return (u16)((u + 0x7FFFu + ((u >> 16) & 1u)) >> 16);
}

// ws layout (u16 elements): [0)      W1t[n][k]   256x256
//                           [65536)  W2t[n][k]   256x256
//                           [131072) Wht[c][k]   512x256, c = r*128 + a
__global__ void prep_weights(const float* __restrict__ W1,
                             const float* __restrict__ W2,
                             const float* __restrict__ Wh,
                             u16* __restrict__ ws) {
  int i = blockIdx.x * 256 + threadIdx.x;          // 65536 threads
  int n = i >> 8, k = i & 255;
  ws[i]         = f2bf(W1[k * 256 + n]);           // W1t[n][k] = W1[k][n]
  ws[65536 + i] = f2bf(W2[k * 256 + n]);
#pragma unroll
  for (int t = 0; t < 2; ++t) {
    int idx = i + t * 65536;                        // 131072 elems
    int c = idx >> 8, h = idx & 255;
    int r = c >> 7, a = c & 127;
    ws[131072 + idx] = f2bf(Wh[(r * 256 + h) * 128 + a]);  // Wht[c][h]
  }
}

// One 64x256x(K=256) GEMM: O = relu(A @ Wt^T + bias), A/O bf16 in LDS.
// Wave `wave` (of 8) computes cols [wave*32, wave*32+32).
__device__ __forceinline__ void gemm_256(const u16* A, const u16* __restrict__ Wt,
                                         const float* __restrict__ bias, u16* O,
                                         int wave, int ar, int kg, int orow) {
  f32x4 acc[4][2] = {};
  const int n0 = wave * 32;
#pragma unroll
  for (int kk = 0; kk < 8; ++kk) {
    const int k = kk * 32 + kg;
    bf16x8 a[4], b[2];
#pragma unroll
    for (int m = 0; m < 4; ++m)
      a[m] = *(const bf16x8*)&A[(m * 16 + ar) * LDSW + k];
#pragma unroll
    for (int n = 0; n < 2; ++n)
      b[n] = *(const bf16x8*)&Wt[(n0 + n * 16 + ar) * 256 + k];
#pragma unroll
    for (int m = 0; m < 4; ++m)
#pragma unroll
      for (int n = 0; n < 2; ++n)
        acc[m][n] = __builtin_amdgcn_mfma_f32_16x16x32_bf16(a[m], b[n], acc[m][n], 0, 0, 0);
  }
#pragma unroll
  for (int n = 0; n < 2; ++n) {
    const int col = n0 + n * 16 + ar;
    const float bv = bias[col];
#pragma unroll
    for (int m = 0; m < 4; ++m) {
#pragma unroll
      for (int j = 0; j < 4; ++j) {
        float v = acc[m][n][j] + bv;
        v = v > 0.f ? v : 0.f;
        O[(m * 16 + orow + j) * LDSW + col] = f2bf(v);
      }
    }
  }
}

__global__ __launch_bounds__(THREADS, 4) void actor_main(
    const float* __restrict__ x,
    const float* __restrict__ b1, const float* __restrict__ b2,
    const float* __restrict__ bh, const float* __restrict__ log_std,
    const u16* __restrict__ wbf,
    float* __restrict__ out_mean, float* __restrict__ out_std) {
  __shared__ u16 bufA[BM * LDSW];   // x, later feats
  __shared__ u16 bufB[BM * LDSW];   // h
  __shared__ int s_regime[BM];

  const int tid  = threadIdx.x;
  const int lane = tid & 63;
  const int wave = tid >> 6;
  const int row0 = blockIdx.x * BM;
  const int ar   = lane & 15;          // row/col within 16-frag
  const int kg   = (lane >> 4) * 8;    // k sub-offset within 32-chunk
  const int orow = (lane >> 4) * 4;    // C/D row group

  // ---- phase 0: stage x -> bf16 LDS; capture regime from col 255 ----
  {
    const float4* xg = (const float4*)(x + (size_t)row0 * 256);
#pragma unroll
    for (int i = tid; i < BM * 64; i += THREADS) {   // 8 iters
      float4 v = xg[i];
      int row = i >> 6, c4 = (i & 63) << 2;
      ushort4 b;
      b.x = f2bf(v.x); b.y = f2bf(v.y); b.z = f2bf(v.z); b.w = f2bf(v.w);
      *(ushort4*)&bufA[row * LDSW + c4] = b;
      if (c4 == 252) s_regime[row] = (int)v.w;
    }
  }

  // ---- std writes: independent of GEMMs; issue before the barrier so the
  //      store latency overlaps the stage->barrier wait ----
  {
    const int c4 = (tid & 31) << 2;    // constant per thread (512 % 32 == 0)
    float4 s;
    s.x = fminf(fmaxf(expf(log_std[c4 + 0]), 1e-3f), 1.0f);
    s.y = fminf(fmaxf(expf(log_std[c4 + 1]), 1e-3f), 1.0f);
    s.z = fminf(fmaxf(expf(log_std[c4 + 2]), 1e-3f), 1.0f);
    s.w = fminf(fmaxf(expf(log_std[c4 + 3]), 1e-3f), 1.0f);
#pragma unroll
    for (int i = tid; i < BM * 32; i += THREADS) {   // 4 iters
      int row = i >> 5;
      *(float4*)&out_std[(size_t)(row0 + row) * 128 + c4] = s;
    }
  }
  __syncthreads();

  // ---- GEMM1: x @ W1 -> h (bufB) ----
  gemm_256(bufA, wbf, b1, bufB, wave, ar, kg, orow);
  __syncthreads();

  // ---- GEMM2: h @ W2 -> feats (bufA) ----
  gemm_256(bufB, wbf + 65536, b2, bufA, wave, ar, kg, orow);
  __syncthreads();

  // ---- GEMM3: feats @ Wht (N=512: 4 heads concat); wave w owns head w>>1 ----
  {
    const u16* Wht = wbf + 131072;
    f32x4 acc[4][4] = {};
    const int n0 = wave * 64;          // global col in [0,512)
#pragma unroll
    for (int kk = 0; kk < 8; ++kk) {
      const int k = kk * 32 + kg;
      bf16x8 a[4];
#pragma unroll
      for (int m = 0; m < 4; ++m)
        a[m] = *(const bf16x8*)&bufA[(m * 16 + ar) * LDSW + k];
#pragma unroll
      for (int n = 0; n < 4; ++n) {
        bf16x8 b = *(const bf16x8*)&Wht[(n0 + n * 16 + ar) * 256 + k];
#pragma unroll
        for (int m = 0; m < 4; ++m)
          acc[m][n] = __builtin_amdgcn_mfma_f32_16x16x32_bf16(a[m], b, acc[m][n], 0, 0, 0);
      }
    }
    // epilogue: this wave's 64 cols all belong to head wave>>1
    const int head = wave >> 1;
    const int c0   = (wave & 1) * 64;
#pragma unroll
    for (int n = 0; n < 4; ++n) {
      const int acol = c0 + n * 16 + ar;            // 0..127 within head
      const float bhv = bh[head * 128 + acol];
#pragma unroll
      for (int m = 0; m < 4; ++m) {
#pragma unroll
        for (int j = 0; j < 4; ++j) {
          const int row = m * 16 + orow + j;
          if (s_regime[row] == head)
            out_mean[(size_t)(row0 + row) * 128 + acol] = 0.1f * (acc[m][n][j] + bhv);
        }
      }
    }
  }
}

extern "C" void kernel_launch(void* const* d_in, const int* in_sizes, int n_in,
                              void* d_out, int out_size, void* d_ws, size_t ws_size,
                              hipStream_t stream) {
  const float* x  = (const float*)d_in[0];
  const float* W1 = (const float*)d_in[1];
  const float* b1 = (const float*)d_in[2];
  const float* W2 = (const float*)d_in[3];
  const float* b2 = (const float*)d_in[4];
  const float* Wh = (const float*)d_in[5];
  const float* bh = (const float*)d_in[6];
  const float* ls = (const float*)d_in[7];

  const int B = in_sizes[0] / 256;          // 65536
  float* out_mean = (float*)d_out;
  float* out_std  = out_mean + (size_t)B * 128;
  u16* wbf = (u16*)d_ws;                    // needs 512 KiB

  hipLaunchKernelGGL(prep_weights, dim3(256), dim3(256), 0, stream, W1, W2, Wh, wbf);
  hipLaunchKernelGGL(actor_main, dim3(B / BM), dim3(512), 0, stream,
                     x, b1, b2, bh, ls, wbf, out_mean, out_std);
}

// Round 3
// 66.245 us; speedup vs baseline: 1.7233x; 1.6176x over previous
//
#include <hip/hip_runtime.h>
#include <hip/hip_bf16.h>
#include <cstddef>

// ---------------------------------------------------------------------------
// HardActor: fused regime-routed MLP (bf16 MFMA end-to-end)
//   h     = relu(x @ W1 + b1)            [B,256]
//   feats = relu(h @ W2 + b2)            [B,256]
//   raw   = feats @ Wh[regime] + bh[regime]   (regime = (int)x[:,255])
//   mean  = 0.1 * raw ; std = clip(exp(log_std),1e-3,1) broadcast
//
// R3: weights repacked in prep into PER-WAVE FRAGMENT-CONTIGUOUS order so
// every MFMA B-operand load is a lane-contiguous 1KB global load (ideal
// coalescing) instead of a 16-cache-line scatter (R2: lane stride 512B ->
// ~16 L2 transactions per load, TCP-serialized). GEMM1 B-frags preloaded
// before the stage barrier; GEMM2's issued during GEMM1 epilogue.
// ---------------------------------------------------------------------------

typedef unsigned short u16;
typedef unsigned int   u32;

using bf16x8 = __attribute__((ext_vector_type(8))) __bf16;
using f32x4  = __attribute__((ext_vector_type(4))) float;

#define BM      64
#define LDSW    264   // 256 + 8 bf16 pad: 16B row alignment, breaks bank aliasing
#define THREADS 512

__device__ __forceinline__ u16 f2bf(float f) {
  union { float f; u32 u; } v; v.f = f;
  u32 u = v.u;
  return (u16)((u + 0x7FFFu + ((u >> 16) & 1u)) >> 16);
}

// Packed ws layout (u16 elements), fragment order for 8-wave blocks:
//  W1p [0)      : [w:8][nb:2][kk:8][lane:64][j:8]   (65536)  n=w*32+nb*16+(l&15), k=kk*32+(l>>4)*8+j
//  W2p [65536)  : same                               (65536)
//  Whp [131072) : [w:8][nb:4][kk:8][lane:64][j:8]   (131072) c=w*64+nb*16+(l&15) -> head c>>7, a=c&127
__global__ void prep_weights(const float* __restrict__ W1,
                             const float* __restrict__ W2,
                             const float* __restrict__ Wh,
                             u16* __restrict__ ws) {
  int i = blockIdx.x * 256 + threadIdx.x;          // [0, 65536)
  {
    int j  = i & 7, l = (i >> 3) & 63, kk = (i >> 9) & 7;
    int nb = (i >> 12) & 1, w = i >> 13;
    int n = w * 32 + nb * 16 + (l & 15);
    int k = kk * 32 + ((l >> 4) << 3) + j;
    ws[i]         = f2bf(W1[k * 256 + n]);
    ws[65536 + i] = f2bf(W2[k * 256 + n]);
  }
#pragma unroll
  for (int t = 0; t < 2; ++t) {
    int idx = i + t * 65536;                        // [0, 131072)
    int j  = idx & 7, l = (idx >> 3) & 63, kk = (idx >> 9) & 7;
    int nb = (idx >> 12) & 3, w = idx >> 14;
    int c = w * 64 + nb * 16 + (l & 15);            // col in [0,512)
    int k = kk * 32 + ((l >> 4) << 3) + j;
    int r = c >> 7, a = c & 127;
    ws[131072 + idx] = f2bf(Wh[(r * 256 + k) * 128 + a]);
  }
}

__device__ __forceinline__ void load_bfrags16(bf16x8 b[2][8], const u16* __restrict__ Wp,
                                              int lane) {
#pragma unroll
  for (int nb = 0; nb < 2; ++nb)
#pragma unroll
    for (int kk = 0; kk < 8; ++kk)
      b[nb][kk] = *(const bf16x8*)&Wp[(((nb * 8) + kk) * 64 + lane) * 8];
}

__device__ __forceinline__ void mfma_256(f32x4 acc[4][2], const u16* A,
                                         const bf16x8 b[2][8], int ar, int kg) {
#pragma unroll
  for (int kk = 0; kk < 8; ++kk) {
    const int k = kk * 32 + kg;
    bf16x8 a[4];
#pragma unroll
    for (int m = 0; m < 4; ++m)
      a[m] = *(const bf16x8*)&A[(m * 16 + ar) * LDSW + k];
#pragma unroll
    for (int m = 0; m < 4; ++m)
#pragma unroll
      for (int nb = 0; nb < 2; ++nb)
        acc[m][nb] = __builtin_amdgcn_mfma_f32_16x16x32_bf16(a[m], b[nb][kk], acc[m][nb], 0, 0, 0);
  }
}

__device__ __forceinline__ void epilogue_relu(f32x4 acc[4][2], const float* __restrict__ bias,
                                              u16* O, int n0, int ar, int orow) {
#pragma unroll
  for (int nb = 0; nb < 2; ++nb) {
    const int col = n0 + nb * 16 + ar;
    const float bv = bias[col];
#pragma unroll
    for (int m = 0; m < 4; ++m) {
#pragma unroll
      for (int j = 0; j < 4; ++j) {
        float v = acc[m][nb][j] + bv;
        v = v > 0.f ? v : 0.f;
        O[(m * 16 + orow + j) * LDSW + col] = f2bf(v);
      }
    }
  }
}

__global__ __launch_bounds__(THREADS, 4) void actor_main(
    const float* __restrict__ x,
    const float* __restrict__ b1, const float* __restrict__ b2,
    const float* __restrict__ bh, const float* __restrict__ log_std,
    const u16* __restrict__ wbf,
    float* __restrict__ out_mean, float* __restrict__ out_std) {
  __shared__ u16 bufA[BM * LDSW];   // x, later feats
  __shared__ u16 bufB[BM * LDSW];   // h
  __shared__ int s_regime[BM];

  const int tid  = threadIdx.x;
  const int lane = tid & 63;
  const int wave = tid >> 6;
  const int row0 = blockIdx.x * BM;
  const int ar   = lane & 15;          // row/col within 16-frag
  const int kg   = (lane >> 4) * 8;    // k sub-offset within 32-chunk
  const int orow = (lane >> 4) * 4;    // C/D row group
  const int n0   = wave * 32;          // GEMM1/2 col base

  // ---- preload GEMM1 B-fragments (global-only dependency; overlaps staging) ----
  bf16x8 bw1[2][8];
  load_bfrags16(bw1, wbf + wave * 8192, lane);

  // ---- phase 0: stage x -> bf16 LDS; capture regime from col 255 ----
  {
    const float4* xg = (const float4*)(x + (size_t)row0 * 256);
#pragma unroll
    for (int i = tid; i < BM * 64; i += THREADS) {   // 8 iters
      float4 v = xg[i];
      int row = i >> 6, c4 = (i & 63) << 2;
      ushort4 b;
      b.x = f2bf(v.x); b.y = f2bf(v.y); b.z = f2bf(v.z); b.w = f2bf(v.w);
      *(ushort4*)&bufA[row * LDSW + c4] = b;
      if (c4 == 252) s_regime[row] = (int)v.w;
    }
  }

  // ---- std writes (independent of GEMMs; overlap the barrier wait) ----
  {
    const int c4 = (tid & 31) << 2;
    float4 s;
    s.x = fminf(fmaxf(expf(log_std[c4 + 0]), 1e-3f), 1.0f);
    s.y = fminf(fmaxf(expf(log_std[c4 + 1]), 1e-3f), 1.0f);
    s.z = fminf(fmaxf(expf(log_std[c4 + 2]), 1e-3f), 1.0f);
    s.w = fminf(fmaxf(expf(log_std[c4 + 3]), 1e-3f), 1.0f);
#pragma unroll
    for (int i = tid; i < BM * 32; i += THREADS) {   // 4 iters
      int row = i >> 5;
      *(float4*)&out_std[(size_t)(row0 + row) * 128 + c4] = s;
    }
  }
  __syncthreads();

  // ---- GEMM1: x @ W1 -> h (bufB) ----
  {
    f32x4 acc[4][2] = {};
    mfma_256(acc, bufA, bw1, ar, kg);
    epilogue_relu(acc, b1, bufB, n0, ar, orow);
  }
  // ---- preload GEMM2 B-frags (bw1 dead; overlaps epilogue + barrier) ----
  bf16x8 bw2[2][8];
  load_bfrags16(bw2, wbf + 65536 + wave * 8192, lane);
  __syncthreads();

  // ---- GEMM2: h @ W2 -> feats (bufA) ----
  {
    f32x4 acc[4][2] = {};
    mfma_256(acc, bufB, bw2, ar, kg);
    epilogue_relu(acc, b2, bufA, n0, ar, orow);
  }
  __syncthreads();

  // ---- GEMM3: feats @ Whp (N=512, 4 heads concat); wave w owns head w>>1 ----
  {
    const u16* __restrict__ Wp3 = wbf + 131072 + wave * 16384;
    f32x4 acc[4][4] = {};
#pragma unroll 2
    for (int kk = 0; kk < 8; ++kk) {
      const int k = kk * 32 + kg;
      bf16x8 a[4], b[4];
#pragma unroll
      for (int nb = 0; nb < 4; ++nb)
        b[nb] = *(const bf16x8*)&Wp3[((nb * 8 + kk) * 64 + lane) * 8];
#pragma unroll
      for (int m = 0; m < 4; ++m)
        a[m] = *(const bf16x8*)&bufA[(m * 16 + ar) * LDSW + k];
#pragma unroll
      for (int m = 0; m < 4; ++m)
#pragma unroll
        for (int nb = 0; nb < 4; ++nb)
          acc[m][nb] = __builtin_amdgcn_mfma_f32_16x16x32_bf16(a[m], b[nb], acc[m][nb], 0, 0, 0);
    }
    // epilogue: this wave's 64 cols all belong to head wave>>1
    const int head = wave >> 1;
    const int c0   = (wave & 1) * 64;
#pragma unroll
    for (int nb = 0; nb < 4; ++nb) {
      const int acol = c0 + nb * 16 + ar;           // 0..127 within head
      const float bhv = bh[head * 128 + acol];
#pragma unroll
      for (int m = 0; m < 4; ++m) {
#pragma unroll
        for (int j = 0; j < 4; ++j) {
          const int row = m * 16 + orow + j;
          if (s_regime[row] == head)
            out_mean[(size_t)(row0 + row) * 128 + acol] = 0.1f * (acc[m][nb][j] + bhv);
        }
      }
    }
  }
}

extern "C" void kernel_launch(void* const* d_in, const int* in_sizes, int n_in,
                              void* d_out, int out_size, void* d_ws, size_t ws_size,
                              hipStream_t stream) {
  const float* x  = (const float*)d_in[0];
  const float* W1 = (const float*)d_in[1];
  const float* b1 = (const float*)d_in[2];
  const float* W2 = (const float*)d_in[3];
  const float* b2 = (const float*)d_in[4];
  const float* Wh = (const float*)d_in[5];
  const float* bh = (const float*)d_in[6];
  const float* ls = (const float*)d_in[7];

  const int B = in_sizes[0] / 256;          // 65536
  float* out_mean = (float*)d_out;
  float* out_std  = out_mean + (size_t)B * 128;
  u16* wbf = (u16*)d_ws;                    // needs 512 KiB

  hipLaunchKernelGGL(prep_weights, dim3(256), dim3(256), 0, stream, W1, W2, Wh, wbf);
  hipLaunchKernelGGL(actor_main, dim3(B / BM), dim3(512), 0, stream,
                     x, b1, b2, bh, ls, wbf, out_mean, out_std);
}